// Round 1
// baseline (367.372 us; speedup 1.0000x reference)
//
#include <hip/hip_runtime.h>

// LearnableWaveletTransform: depthwise conv1d (shared filter), K=96, pad=48,
// x (64,128,4096) f32 -> (l_out, h_out) each (64,128,4097) f32.
// y_f[t] = sum_{k=0}^{95} x[t-48+k] * w_f[k]
//
// R3: wave-autonomous streaming. One block per row: stage the whole row as
// bf16 once (one barrier total), then each wave owns t in [1024w,1024w+1024)
// and runs 4 phases of {2 MFMA tiles -> per-wave skewed bounce -> coalesced
// stores} with NO further barriers (same-wave LDS ops are in-order; the
// compiler inserts lgkmcnt waits). Kills: 3 of 4 barrier drains per 4096
// outputs, the cross-wave store barrier, and the 6% halo re-read of R2.
// Skew i+8*(i>>5): scatter writes land on banks (8q+8r+s) mod 32 = all 32
// exactly once per filter (conflict-free); readback is <=2-way (free).
// LDS 18.7 KB -> 8 blocks/CU LDS-limit. Accum fp32; absmax ~0.03 << 0.117.

#define KW    96
#define PADW  48
#define T_IN  4096
#define T_OUT 4097
#define ROWS  8192           // 64*128
#define BLOCK 256
#define NF4   1056           // staged float4s per row: covers x[-48 .. 4176)
#define XSH   (NF4 * 4)      // 4224 bf16 elements = 528 granules
#define BNC   320            // skewed dwords per (wave,filter) bounce region

typedef __attribute__((ext_vector_type(8))) short short8;
typedef __attribute__((ext_vector_type(4))) float f32x4;

__device__ __forceinline__ unsigned short f2bf(float v) {
    unsigned u = __builtin_bit_cast(unsigned, v);
    u += 0x7FFFu + ((u >> 16) & 1u);      // RNE (inputs are finite gaussians)
    return (unsigned short)(u >> 16);
}

// ---- init: build per-lane B-fragments (identical for every block) ----
// B[k][n] = w_f[k-s], n = f*8+s (f: 0=l 1=h, s=0..7), k in [0,128) (pad->0).
// Lane L holds B[k = (L>>4)*8 + j + 32c][n = L&15], j=0..7, chunk c=0..3.
// Thread t = L*4+c writes its 8 bf16 (16 B) at ws[t*16B].
__global__ __launch_bounds__(BLOCK) void lwt_init(
    const float* __restrict__ hw, const float* __restrict__ lw,
    unsigned short* __restrict__ ws)
{
    const int t = threadIdx.x;
    const int L = t >> 2, c = t & 3;
    const int n = L & 15, q = L >> 4;
    const int s = n & 7, f = n >> 3;
    const float* w = f ? hw : lw;
    unsigned short b[8];
    #pragma unroll
    for (int j = 0; j < 8; ++j) {
        const int k = 32 * c + 8 * q + j;
        const int kk = k - s;
        b[j] = (kk >= 0 && kk < KW) ? f2bf(w[kk]) : (unsigned short)0;
    }
    uint4 pk;
    pk.x = (unsigned)b[0] | ((unsigned)b[1] << 16);
    pk.y = (unsigned)b[2] | ((unsigned)b[3] << 16);
    pk.z = (unsigned)b[4] | ((unsigned)b[5] << 16);
    pk.w = (unsigned)b[6] | ((unsigned)b[7] << 16);
    ((uint4*)ws)[t] = pk;
}

__global__ __launch_bounds__(BLOCK, 4) void lwt_main(
    const float* __restrict__ x,
    const float* __restrict__ hw,
    const float* __restrict__ lw,
    const unsigned short* __restrict__ ws,
    float* __restrict__ out_l,
    float* __restrict__ out_h)
{
    __shared__ alignas(16) unsigned short xs[XSH];     // 8448 B
    __shared__ float bounce[4][2][BNC];                // 10240 B
    const int bid = blockIdx.x;
    const int tid = threadIdx.x;

    if (bid < ROWS) {
        const int lane = tid & 63;

        // ---- B fragments first (independent; overlap with staging) ----
        const short8* wsB = (const short8*)ws;
        short8 bf0 = wsB[lane * 4 + 0];
        short8 bf1 = wsB[lane * 4 + 1];
        short8 bf2 = wsB[lane * 4 + 2];
        short8 bf3 = wsB[lane * 4 + 3];

        // ---- stage x[-48 .. 4176) as bf16 into LDS (zero OOB) ----
        // All float4s are entirely in- or out-of-bounds (offsets % 4 == 0).
        const float* xrow = x + (size_t)bid * T_IN;
        for (int i = tid; i < NF4; i += BLOCK) {
            const int g = 4 * i - PADW;
            float4 v = make_float4(0.f, 0.f, 0.f, 0.f);
            if (g >= 0 && g < T_IN) v = *(const float4*)(xrow + g);
            ushort4 u;
            u.x = f2bf(v.x); u.y = f2bf(v.y); u.z = f2bf(v.z); u.w = f2bf(v.w);
            *(ushort4*)(xs + 4 * i) = u;
        }
        __syncthreads();     // the ONLY barrier

        // ---- per-wave: 4 phases x (2 tiles MFMA -> bounce -> store) ----
        const int wv = tid >> 6;
        const int m  = lane & 15;         // A-operand row
        const int q  = lane >> 4;         // A/B k-quad == D row-quad
        const int sD = m & 7;             // D col -> (filter, shift)
        const int fD = m >> 3;
        const short8* ap = (const short8*)xs;   // 16-B granules
        float* bw = &bounce[wv][fD][0];
        const size_t ob = (size_t)bid * T_OUT + (size_t)wv * 1024;

        #pragma unroll 1
        for (int ph = 0; ph < 4; ++ph) {
            #pragma unroll
            for (int it = 0; it < 2; ++it) {
                const int tile = wv * 8 + ph * 2 + it;
                const int ga0 = tile * 16 + m + q;    // + 4c per chunk
                f32x4 acc = {0.f, 0.f, 0.f, 0.f};
                acc = __builtin_amdgcn_mfma_f32_16x16x32_bf16(ap[ga0     ], bf0, acc, 0, 0, 0);
                acc = __builtin_amdgcn_mfma_f32_16x16x32_bf16(ap[ga0 +  4], bf1, acc, 0, 0, 0);
                acc = __builtin_amdgcn_mfma_f32_16x16x32_bf16(ap[ga0 +  8], bf2, acc, 0, 0, 0);
                acc = __builtin_amdgcn_mfma_f32_16x16x32_bf16(ap[ga0 + 12], bf3, acc, 0, 0, 0);
                // D[row = q*4 + r][col = m] -> i0 = it*128 + 32q + 8r + sD
                #pragma unroll
                for (int r = 0; r < 4; ++r) {
                    const int i0 = it * 128 + 32 * q + 8 * r + sD;
                    bw[i0 + 8 * (i0 >> 5)] = acc[r];   // conflict-free scatter
                }
            }
            // wave-local readback + coalesced stores (no barrier needed:
            // same-wave LDS ops execute in order)
            const int tb = ph * 256;
            #pragma unroll
            for (int p = 0; p < 4; ++p) {
                const int i = lane + 64 * p;
                out_l[ob + tb + i] = bounce[wv][0][i + 8 * (i >> 5)];
            }
            #pragma unroll
            for (int p = 0; p < 4; ++p) {
                const int i = lane + 64 * p;
                out_h[ob + tb + i] = bounce[wv][1][i + 8 * (i >> 5)];
            }
        }
    } else {
        // ---- tail: column t=4096 (only taps k<48 in-bounds), exact fp32 ----
        const int r = (bid - ROWS) * BLOCK + tid;
        if (r < ROWS) {
            const float* xp = x + (size_t)r * T_IN + (T_OUT - 1 - PADW);
            float al = 0.f, ah = 0.f;
            #pragma unroll
            for (int k = 0; k < PADW; ++k) {
                const float xv = xp[k];
                al = fmaf(xv, lw[k], al);
                ah = fmaf(xv, hw[k], ah);
            }
            const size_t o = (size_t)r * T_OUT + (T_OUT - 1);
            out_l[o] = al;
            out_h[o] = ah;
        }
    }
}

extern "C" void kernel_launch(void* const* d_in, const int* in_sizes, int n_in,
                              void* d_out, int out_size, void* d_ws, size_t ws_size,
                              hipStream_t stream) {
    const float* x  = (const float*)d_in[0];
    const float* hw = (const float*)d_in[1];  // h_w (96)
    const float* lw = (const float*)d_in[2];  // l_w (96)
    float* out_l = (float*)d_out;             // l_outs first (return order)
    float* out_h = out_l + (size_t)ROWS * T_OUT;
    unsigned short* wsB = (unsigned short*)d_ws;   // 4 KB of B-fragments

    lwt_init<<<1, BLOCK, 0, stream>>>(hw, lw, wsB);
    const int grid = ROWS + ROWS / BLOCK;
    lwt_main<<<grid, BLOCK, 0, stream>>>(x, hw, lw, wsB, out_l, out_h);
}